// Round 10
// baseline (147.232 us; speedup 1.0000x reference)
//
#include <hip/hip_runtime.h>
#include <hip/hip_bf16.h>
#include <math.h>

#define CNUM 20
#define KNUM 64
#define DDIM 256
#define SEGS 32

typedef __attribute__((ext_vector_type(8))) short short8;
typedef __attribute__((ext_vector_type(4))) unsigned short u16x4;
typedef __attribute__((ext_vector_type(4))) float f32x4;

static __device__ __forceinline__ float shfl_xor_f(float v, int m) {
    return __shfl_xor(v, m, 64);
}

static __device__ __forceinline__ unsigned short f2bf(float f) {
    union { float f; unsigned u; } x; x.f = f;
    unsigned r = x.u + 0x7FFF + ((x.u >> 16) & 1);   // RTN-even
    return (unsigned short)(r >> 16);
}

static __device__ __forceinline__ float bf2f(unsigned short h) {
    union { unsigned u; float f; } x; x.u = ((unsigned)h) << 16;
    return x.f;
}

// ---- K_A: fused setup. blocks [0,320): per-(c,k) stats + mu->bf16 (4 ck/block);
// ----      blocks [320,320+HB): label histogram at 64-sample-group granularity ----
__global__ void k_setup(const float* __restrict__ mu, const float* __restrict__ exp_temp,
                        const float* __restrict__ runa, const float* __restrict__ runb,
                        const float* __restrict__ med, const float* __restrict__ stdv,
                        const int* __restrict__ labels, int N,
                        float* __restrict__ mu2, float* __restrict__ rtau,
                        float* __restrict__ ltau, float* __restrict__ vldf,
                        float* __restrict__ rstd, float* __restrict__ mrs,
                        unsigned short* __restrict__ mubf, int* __restrict__ bc)
{
    __shared__ int h4[4 * CNUM];
    const int bid = blockIdx.x, tid = threadIdx.x;
    if (bid < 320) {
        const int w = tid >> 6, lane = tid & 63;
        if (bid == 0) {
            const float r = 1.0f / stdv[tid];           // blockDim==DDIM==256
            rstd[tid] = r;
            mrs[tid] = med[tid] * r;
        }
        const int ck = bid * 4 + w;                      // covers [0, 1280)
        const float4 v = *(const float4*)(mu + (size_t)ck * DDIM + lane * 4);
        u16x4 pk;
        pk[0] = f2bf(v.x); pk[1] = f2bf(v.y); pk[2] = f2bf(v.z); pk[3] = f2bf(v.w);
        *(u16x4*)(mubf + (size_t)ck * DDIM + lane * 4) = pk;
        float s = v.x * v.x + v.y * v.y + v.z * v.z + v.w * v.w;
#pragma unroll
        for (int off = 32; off > 0; off >>= 1) s += shfl_xor_f(s, off);
        if (lane == 0) {
            mu2[ck] = s;
            const float e = exp_temp[ck];
            const float t = 100.0f / (1.0f + __expf(-0.5f * e)) + 0.01f;
            rtau[ck] = 1.0f / t;
            ltau[ck] = logf(t);
            const int c = ck >> 6;
            const float thr = runb[c] * (0.5f / (float)KNUM);
            vldf[ck] = (runa[ck] > thr) ? 1.0f : 0.0f;
        }
    } else {
        const int hb = bid - 320;                        // 4 groups of 64 per block
        if (tid < 4 * CNUM) h4[tid] = 0;
        __syncthreads();
        const int i = hb * 256 + tid;
        if (i < N) atomicAdd(&h4[(tid >> 6) * CNUM + labels[i]], 1);
        __syncthreads();
        if (tid < 4 * CNUM)
            bc[(hb * 4 + tid / CNUM) * CNUM + (tid % CNUM)] = h4[tid];
    }
}

// ---- K_B: counts, padded class offsets, per-group bases, block->class map ----
__global__ void k_scan(const int* __restrict__ bc, int ngrp, int* __restrict__ cnt,
                       int* __restrict__ ps, int* __restrict__ sb,
                       int* __restrict__ blk2cls)
{
    __shared__ int part[SEGS][CNUM];
    __shared__ int psl[CNUM + 1];
    const int tid = threadIdx.x;
    const int spb = (ngrp + SEGS - 1) / SEGS;
    if (tid < SEGS * CNUM) {
        const int c = tid % CNUM, seg = tid / CNUM;
        const int b0 = seg * spb, b1 = min(b0 + spb, ngrp);
        int s = 0;
        for (int b = b0; b < b1; ++b) s += bc[b * CNUM + c];
        part[seg][c] = s;
    }
    __syncthreads();
    if (tid < CNUM) {
        int s = 0;
#pragma unroll
        for (int g = 0; g < SEGS; ++g) s += part[g][tid];
        cnt[tid] = s;
    }
    __syncthreads();
    if (tid == 0) {
        int run = 0;
        for (int c = 0; c < CNUM; ++c) {
            psl[c] = run; ps[c] = run;
            run += (cnt[c] + 63) & ~63;
        }
        psl[CNUM] = run; ps[CNUM] = run;
    }
    __syncthreads();
    if (tid < SEGS * CNUM) {
        const int c = tid % CNUM, seg = tid / CNUM;
        int run = psl[c];
        for (int g = 0; g < seg; ++g) run += part[g][c];
        const int b0 = seg * spb, b1 = min(b0 + spb, ngrp);
        for (int b = b0; b < b1; ++b) { sb[b * CNUM + c] = run; run += bc[b * CNUM + c]; }
    }
    __syncthreads();
    if (tid < CNUM) {
        const int b0 = psl[tid] >> 6, b1 = psl[tid + 1] >> 6;
        for (int b = b0; b < b1; ++b) blk2cls[b] = tid;
    }
}

// ---- K_C: 64 samples/block (2048 blocks -> full occupancy streaming).
// ----      Sequential read+normalize+pack; block-major sequential write; src[] map. ----
__global__ __launch_bounds__(256, 8)
void k_scnorm(const float* __restrict__ data, const float* __restrict__ mrs,
              const float* __restrict__ rstd, const int* __restrict__ labels, int N,
              const int* __restrict__ sb, unsigned short* __restrict__ xs,
              int* __restrict__ src)
{
    __shared__ int lcls[64];
    __shared__ int dstloc[64];
    __shared__ int hcnt[CNUM];
    __shared__ int clsoff[CNUM];
    const int tid = threadIdx.x, w = tid >> 6, lane = tid & 63;
    const int grp = blockIdx.x;
    const int base = grp * 64;
    if (tid < 64) lcls[tid] = (base + tid < N) ? labels[base + tid] : -1;
    __syncthreads();
    if (tid < CNUM) {
        int s = 0;
#pragma unroll 8
        for (int j = 0; j < 64; ++j) s += (lcls[j] == tid);
        hcnt[tid] = s;
    }
    int r = 0, c = -1;
    if (tid < 64) {
        c = lcls[tid];
        for (int j = 0; j < tid; ++j) r += (lcls[j] == c);
    }
    __syncthreads();
    if (tid == 0) {
        int run = 0;
        for (int cc = 0; cc < CNUM; ++cc) { clsoff[cc] = run; run += hcnt[cc]; }
    }
    __syncthreads();
    if (tid < 64 && base + tid < N) {
        const int dl = clsoff[c] + r;
        dstloc[tid] = dl;
        src[sb[grp * CNUM + c] + r] = base + dl;         // tiny 4B scatter
    }
    __syncthreads();

    // streaming: wave w handles rows [16w, 16w+16), 1KB coalesced per row
    const float4 m4 = *(const float4*)(mrs + 4 * lane);
    const float4 r4 = *(const float4*)(rstd + 4 * lane);
    const float* __restrict__ src0 = data + (size_t)(base + 16 * w) * DDIM + 4 * lane;
    const int nrow = min(16, N - (base + 16 * w));
    if (nrow == 16) {
#pragma unroll 1
        for (int j = 0; j < 16; j += 4) {
            const float4 u0 = *(const float4*)(src0 + (size_t)(j + 0) * DDIM);
            const float4 u1 = *(const float4*)(src0 + (size_t)(j + 1) * DDIM);
            const float4 u2 = *(const float4*)(src0 + (size_t)(j + 2) * DDIM);
            const float4 u3 = *(const float4*)(src0 + (size_t)(j + 3) * DDIM);
#pragma unroll
            for (int t = 0; t < 4; ++t) {
                const float4 u = (t == 0) ? u0 : (t == 1) ? u1 : (t == 2) ? u2 : u3;
                const int dl = dstloc[16 * w + j + t];
                union { uint2 u2v; __hip_bfloat162 b2[2]; } pk;
                pk.b2[0] = __float22bfloat162_rn(
                    float2{fmaf(u.x, r4.x, -m4.x), fmaf(u.y, r4.y, -m4.y)});
                pk.b2[1] = __float22bfloat162_rn(
                    float2{fmaf(u.z, r4.z, -m4.z), fmaf(u.w, r4.w, -m4.w)});
                *(uint2*)((unsigned char*)xs + ((size_t)base + dl) * 512 + 8 * lane) = pk.u2v;
            }
        }
    } else if (nrow > 0) {
        for (int j = 0; j < nrow; ++j) {
            const float4 u = *(const float4*)(src0 + (size_t)j * DDIM);
            const int dl = dstloc[16 * w + j];
            union { uint2 u2v; __hip_bfloat162 b2[2]; } pk;
            pk.b2[0] = __float22bfloat162_rn(
                float2{fmaf(u.x, r4.x, -m4.x), fmaf(u.y, r4.y, -m4.y)});
            pk.b2[1] = __float22bfloat162_rn(
                float2{fmaf(u.z, r4.z, -m4.z), fmaf(u.w, r4.w, -m4.w)});
            *(uint2*)((unsigned char*)xs + ((size_t)base + dl) * 512 + 8 * lane) = pk.u2v;
        }
    }
}

// ---- K_D: MFMA — X staged via global_load_lds (swizzled src, wave-local, NO barrier);
// ----      mu fragments read per-lane from L2 (class tile is L2-hot). ----
__global__ __launch_bounds__(256, 4)
void k_mfma(const unsigned short* __restrict__ xs, const int* __restrict__ src,
            const unsigned short* __restrict__ mubf,
            const float* __restrict__ mu2, const float* __restrict__ rtau,
            const float* __restrict__ ltau, const float* __restrict__ vldf,
            const int* __restrict__ ps, const int* __restrict__ cnt,
            const int* __restrict__ blk2cls, float* __restrict__ wpart)
{
    __shared__ __align__(16) unsigned char Xb[64 * 512];   // bf16 rows, swizzled
    const int tid = threadIdx.x, w = tid >> 6, lane = tid & 63;
    const int g = blockIdx.x;
    const int slot0 = g * 64;
    const int padtot = ps[CNUM];
    if (slot0 >= padtot) { if (lane == 0) wpart[g * 4 + w] = 0.f; return; }
    const int c = blk2cls[g];
    const int relast = ps[c] + cnt[c] - 1;

    const int h2 = lane >> 5;
    const int m31b = 16 * (lane & 31);
    int nid[8];
#pragma unroll
    for (int pr = 0; pr < 8; ++pr) {
        const int slot = slot0 + 16 * w + 2 * pr + h2;
        nid[pr] = src[min(slot, relast)];                // pads duplicate a real row
    }
#pragma unroll
    for (int pr = 0; pr < 8; ++pr) {
        const int lr = 16 * w + 2 * pr + h2;             // local row this lane fills
        const int sw = 16 * (lr & 7);
        const unsigned char* sx = (const unsigned char*)xs
            + (size_t)nid[pr] * 512 + (m31b ^ sw);       // pre-swizzled global source
        void* dx = (void*)(Xb + (size_t)(16 * w + 2 * pr) * 512);  // linear dest
        __builtin_amdgcn_global_load_lds(
            (const __attribute__((address_space(1))) void*)sx,
            (__attribute__((address_space(3))) void*)dx, 16, 0, 0);
    }
    asm volatile("s_waitcnt vmcnt(0)" ::: "memory");     // wave-local rows: no barrier

    const int n16 = lane & 15, kg = lane >> 4;
    const int Sb = 16 * (n16 & 7);
    const unsigned char* __restrict__ xrd = Xb + (size_t)(16 * w + n16) * 512;

    short8 xb[8];
#pragma unroll
    for (int s = 0; s < 8; ++s)
        xb[s] = *(const short8*)(xrd + ((64 * s + 16 * kg) ^ Sb));

    // MFMA with A-frag (mu) prefetch one K-step ahead (L2-resident class tile)
    const unsigned short* __restrict__ mbase =
        mubf + ((size_t)c * KNUM + n16) * DDIM + 8 * kg;
    short8 afn[4];
#pragma unroll
    for (int f = 0; f < 4; ++f) afn[f] = *(const short8*)(mbase + f * 16 * DDIM);
    f32x4 acc[4] = {};
#pragma unroll
    for (int s = 0; s < 8; ++s) {
        short8 af[4];
#pragma unroll
        for (int f = 0; f < 4; ++f) af[f] = afn[f];
        if (s < 7) {
#pragma unroll
            for (int f = 0; f < 4; ++f)
                afn[f] = *(const short8*)(mbase + f * 16 * DDIM + 32 * (s + 1));
        }
#pragma unroll
        for (int f = 0; f < 4; ++f)
            acc[f] = __builtin_amdgcn_mfma_f32_16x16x32_bf16(af[f], xb[s], acc[f], 0, 0, 0);
    }

    // |x|^2 from the bf16 fragments (consistent with the dot)
    float q = 0.f;
#pragma unroll
    for (int s = 0; s < 8; ++s)
#pragma unroll
        for (int j = 0; j < 8; ++j) {
            const float f = bf2f((unsigned short)xb[s][j]);
            q = fmaf(f, f, q);
        }
    q += shfl_xor_f(q, 16);
    q += shfl_xor_f(q, 32);

    // epilogue: lane holds 16 k-values (k = 16f + 4kg + r) of its sample
    const int ckb = c * KNUM;
    float simv[16], lpv[16];
    float mxv = -3.4e38f;
#pragma unroll
    for (int f = 0; f < 4; ++f) {
        const int kb = ckb + 16 * f + 4 * kg;
        const float4 m2v = *(const float4*)(mu2 + kb);
        const float4 rtv = *(const float4*)(rtau + kb);
        const float4 ltv = *(const float4*)(ltau + kb);
        const float4 vlv = *(const float4*)(vldf + kb);
#pragma unroll
        for (int r = 0; r < 4; ++r) {
            const float m2 = (&m2v.x)[r];
            const float d2 = fmaxf(fmaf(-2.0f, acc[f][r], q + m2), 0.f);
            const float dist = -6.25f * sqrtf(d2);       // 100/sqrt(256)
            const float sim = ((&vlv.x)[r] > 0.5f) ? dist : -1.0e12f;
            simv[4 * f + r] = sim;
            lpv[4 * f + r] = fmaf(sim, (&rtv.x)[r], -(&ltv.x)[r]);
            mxv = fmaxf(mxv, 0.5f * sim);
        }
    }
    mxv = fmaxf(mxv, shfl_xor_f(mxv, 16));
    mxv = fmaxf(mxv, shfl_xor_f(mxv, 32));
    float se = 0.f, sl = 0.f;
#pragma unroll
    for (int i = 0; i < 16; ++i) {
        const float e = __expf(fmaf(0.5f, simv[i], -mxv));
        se += e;
        sl = fmaf(e, lpv[i], sl);
    }
    se += shfl_xor_f(se, 16); se += shfl_xor_f(se, 32);
    sl += shfl_xor_f(sl, 16); sl += shfl_xor_f(sl, 32);
    const int slot = slot0 + 16 * w + n16;
    float res = (kg == 0 && slot <= relast) ? (-sl / se) : 0.f;
    res += shfl_xor_f(res, 1);
    res += shfl_xor_f(res, 2);
    res += shfl_xor_f(res, 4);
    res += shfl_xor_f(res, 8);
    if (lane == 0) wpart[g * 4 + w] = res;
}

// ---- K_E: deterministic per-class reduce -> loss ----
__global__ void k_final(const float* __restrict__ wpart, const int* __restrict__ ps,
                        const int* __restrict__ cnt, float* __restrict__ out)
{
    __shared__ float seg[CNUM];
    const int t = threadIdx.x;
    if (t < CNUM) {
        float s = 0.f;
        const int b0 = ps[t] >> 6, b1 = ps[t + 1] >> 6;
        for (int b = b0; b < b1; b++) {
            const float4 v = *(const float4*)(wpart + 4 * b);
            s += ((v.x + v.y) + (v.z + v.w));
        }
        seg[t] = s;
    }
    __syncthreads();
    if (t == 0) {
        float loss = 0.f;
        for (int c = 0; c < CNUM; c++) {
            const float cc = (float)cnt[c];
            if (cc > 0.f) loss += seg[c] / fmaxf(cc, 1.0f);
        }
        out[0] = loss;
    }
}

extern "C" void kernel_launch(void* const* d_in, const int* in_sizes, int n_in,
                              void* d_out, int out_size, void* d_ws, size_t ws_size,
                              hipStream_t stream)
{
    const float* data     = (const float*)d_in[0];
    const int*   labels   = (const int*)d_in[1];
    const float* mu       = (const float*)d_in[2];
    const float* exp_temp = (const float*)d_in[3];
    const float* med      = (const float*)d_in[4];
    const float* stdv     = (const float*)d_in[5];
    const float* runa     = (const float*)d_in[6];
    const float* runb     = (const float*)d_in[7];
    float* out = (float*)d_out;
    const int N = in_sizes[0] / DDIM;
    const int NGRP = (N + 63) / 64;                      // 64-sample groups
    const int HB = (N + 255) / 256;                      // histogram blocks (4 groups each)
    const int idx_slots = N + CNUM * 64;
    const int NB = (idx_slots + 63) / 64;                // mfma blocks

    char* w = (char*)d_ws;
    float* mu2  = (float*)w; w += (size_t)CNUM * KNUM * 4;
    float* rtau = (float*)w; w += (size_t)CNUM * KNUM * 4;
    float* ltau = (float*)w; w += (size_t)CNUM * KNUM * 4;
    float* vldf = (float*)w; w += (size_t)CNUM * KNUM * 4;
    float* rstd = (float*)w; w += (size_t)DDIM * 4;
    float* mrs  = (float*)w; w += (size_t)DDIM * 4;
    unsigned short* mubf = (unsigned short*)w; w += (size_t)CNUM * KNUM * DDIM * 2;
    int* bc  = (int*)w; w += (size_t)NGRP * CNUM * 4;
    int* sb  = (int*)w; w += (size_t)NGRP * CNUM * 4;
    int* cnt = (int*)w; w += 64 * 4;
    int* ps  = (int*)w; w += 64 * 4;
    int* src = (int*)w; w += (size_t)idx_slots * 4;
    int* blk2cls = (int*)w; w += (size_t)NB * 4;
    float* wp = (float*)w; w += (size_t)NB * 4 * 4;
    w = (char*)(((size_t)w + 511) & ~(size_t)511);
    unsigned short* xs = (unsigned short*)w; w += (size_t)N * DDIM * 2;

    k_setup<<<dim3(320 + HB), dim3(256), 0, stream>>>(
        mu, exp_temp, runa, runb, med, stdv, labels, N,
        mu2, rtau, ltau, vldf, rstd, mrs, mubf, bc);
    k_scan<<<dim3(1), dim3(1024), 0, stream>>>(bc, NGRP, cnt, ps, sb, blk2cls);
    k_scnorm<<<dim3(NGRP), dim3(256), 0, stream>>>(data, mrs, rstd, labels, N, sb, xs, src);
    k_mfma<<<dim3(NB), dim3(256), 0, stream>>>(
        xs, src, mubf, mu2, rtau, ltau, vldf, ps, cnt, blk2cls, wp);
    k_final<<<dim3(1), dim3(32), 0, stream>>>(wp, ps, cnt, out);
}

// Round 11
// 129.783 us; speedup vs baseline: 1.1345x; 1.1345x over previous
//
#include <hip/hip_runtime.h>
#include <hip/hip_bf16.h>
#include <math.h>

#define CNUM 20
#define KNUM 64
#define DDIM 256
#define NHB 64

typedef __attribute__((ext_vector_type(8))) short short8;
typedef __attribute__((ext_vector_type(4))) unsigned short u16x4;
typedef __attribute__((ext_vector_type(4))) float f32x4;

static __device__ __forceinline__ float shfl_xor_f(float v, int m) {
    return __shfl_xor(v, m, 64);
}

static __device__ __forceinline__ unsigned short f2bf(float f) {
    union { float f; unsigned u; } x; x.f = f;
    unsigned r = x.u + 0x7FFF + ((x.u >> 16) & 1);   // RTN-even
    return (unsigned short)(r >> 16);
}

// ---- K_A: fused setup. blocks [0,320): per-(c,k) stats + mu->bf16 (4 ck/block);
// ----      blocks [320,384): label histogram (grid-stride, NHB=64 logical blocks) ----
__global__ void k_setup(const float* __restrict__ mu, const float* __restrict__ exp_temp,
                        const float* __restrict__ runa, const float* __restrict__ runb,
                        const float* __restrict__ med, const float* __restrict__ stdv,
                        const int* __restrict__ labels, int N,
                        float* __restrict__ mu2, float* __restrict__ rtau,
                        float* __restrict__ ltau, float* __restrict__ vldf,
                        float* __restrict__ rstd, float* __restrict__ mrs,
                        unsigned short* __restrict__ mubf, int* __restrict__ bc)
{
    __shared__ int h[CNUM];
    const int bid = blockIdx.x, tid = threadIdx.x;
    if (bid < 320) {
        const int w = tid >> 6, lane = tid & 63;
        if (bid == 0) {
            const float r = 1.0f / stdv[tid];           // blockDim==DDIM==256
            rstd[tid] = r;
            mrs[tid] = med[tid] * r;
        }
        const int ck = bid * 4 + w;                      // covers [0, 1280)
        const float4 v = *(const float4*)(mu + (size_t)ck * DDIM + lane * 4);
        u16x4 pk;
        pk[0] = f2bf(v.x); pk[1] = f2bf(v.y); pk[2] = f2bf(v.z); pk[3] = f2bf(v.w);
        *(u16x4*)(mubf + (size_t)ck * DDIM + lane * 4) = pk;
        float s = v.x * v.x + v.y * v.y + v.z * v.z + v.w * v.w;
#pragma unroll
        for (int off = 32; off > 0; off >>= 1) s += shfl_xor_f(s, off);
        if (lane == 0) {
            mu2[ck] = s;
            const float e = exp_temp[ck];
            const float t = 100.0f / (1.0f + __expf(-0.5f * e)) + 0.01f;
            rtau[ck] = 1.0f / t;
            ltau[ck] = logf(t);
            const int c = ck >> 6;
            const float thr = runb[c] * (0.5f / (float)KNUM);
            vldf[ck] = (runa[ck] > thr) ? 1.0f : 0.0f;
        }
    } else {
        const int hb = bid - 320;
        if (tid < CNUM) h[tid] = 0;
        __syncthreads();
        for (int i = hb * 256 + tid; i < N; i += NHB * 256)
            atomicAdd(&h[labels[i]], 1);
        __syncthreads();
        if (tid < CNUM) bc[hb * CNUM + tid] = h[tid];
    }
}

// ---- K_B: scatter (computes its own bases from bc; k_scan eliminated) ----
__global__ void k_scatter(const int* __restrict__ labels, int N,
                          const int* __restrict__ bc, int* __restrict__ idx)
{
    __shared__ int clsc[CNUM];
    __shared__ int cur[CNUM];
    const int tid = threadIdx.x, hb = blockIdx.x;
    if (tid < CNUM) {
        int s = 0;
#pragma unroll 8
        for (int b = 0; b < NHB; ++b) s += bc[b * CNUM + tid];
        clsc[tid] = s;
    }
    __syncthreads();
    if (tid < CNUM) {
        int run = 0;
        for (int c = 0; c < tid; ++c) run += (clsc[c] + 63) & ~63;   // ps[c]
        int before = 0;
        for (int b = 0; b < hb; ++b) before += bc[b * CNUM + tid];
        cur[tid] = run + before;
    }
    __syncthreads();
    for (int i = hb * 256 + tid; i < N; i += NHB * 256) {
        const int c = labels[i];
        const int p = atomicAdd(&cur[c], 1);
        idx[p] = i;
    }
}

// producer helper: stage 16 fp32 rows (1KB each) of one tile quarter into LDS,
// source pre-swizzled (16B granule XOR by row&7), LDS dest linear (rule #21)
static __device__ __forceinline__ void stage_tile(
    const float* __restrict__ data, const int* __restrict__ idx,
    unsigned char* dstbuf, int slot0, int relast, int pw, int lane)
{
#pragma unroll
    for (int i = 0; i < 16; ++i) {
        const int row = 16 * pw + i;
        const int n = idx[min(slot0 + row, relast)];     // wave-uniform scalar load
        const unsigned char* src = (const unsigned char*)(data + (size_t)n * DDIM)
                                   + ((16 * lane) ^ (16 * (row & 7)));
        __builtin_amdgcn_global_load_lds(
            (const __attribute__((address_space(1))) void*)src,
            (__attribute__((address_space(3))) void*)(dstbuf + (size_t)row * 1024),
            16, 0, 0);
    }
}

// ---- K_C: persistent producer/consumer main. 512 thr: waves 4-7 stage (gload_lds,
// ----      double-buffered 2x64KB), waves 0-3 normalize+MFMA+softmax. 1 block/CU. ----
__global__ __launch_bounds__(512, 2)
void k_main(const float* __restrict__ data, const unsigned short* __restrict__ mubf,
            const float* __restrict__ mrs, const float* __restrict__ rstd,
            const float* __restrict__ mu2, const float* __restrict__ rtau,
            const float* __restrict__ ltau, const float* __restrict__ vldf,
            const int* __restrict__ idx, const int* __restrict__ bc,
            float* __restrict__ wpart)
{
    __shared__ __align__(16) unsigned char Xs[2][65536];   // [buf][row 0..63][1KB fp32]
    __shared__ int psL[CNUM + 1];
    __shared__ int cntL[CNUM];
    const int tid = threadIdx.x, w = tid >> 6, lane = tid & 63;

    // in-block scan of bc (replaces k_scan dispatch; once per persistent block)
    if (tid < CNUM) {
        int s = 0;
#pragma unroll 8
        for (int b = 0; b < NHB; ++b) s += bc[b * CNUM + tid];
        cntL[tid] = s;
    }
    __syncthreads();
    if (tid == 0) {
        int run = 0;
        for (int c = 0; c < CNUM; ++c) { psL[c] = run; run += (cntL[c] + 63) & ~63; }
        psL[CNUM] = run;
    }
    __syncthreads();
    const int ntiles = psL[CNUM] >> 6;
    const bool prod = (w >= 4);
    const int sw4 = w & 3;

    // prologue: stage first tile into buf 0
    if (prod) {
        const int t0 = blockIdx.x;
        if (t0 < ntiles) {
            const int s0 = t0 << 6;
            int c = 0; while (c + 1 < CNUM && s0 >= psL[c + 1]) ++c;
            stage_tile(data, idx, Xs[0], s0, psL[c] + cntL[c] - 1, sw4, lane);
        }
        asm volatile("s_waitcnt vmcnt(0)" ::: "memory");
    }
    __syncthreads();

    int ti = 0;
    for (int t = blockIdx.x; t < ntiles; t += gridDim.x, ++ti) {
        if (prod) {
            // ---- stage NEXT tile into the other buffer; stall here = load time,
            // ---- overlapped with consumer compute on the current buffer ----
            const int tn = t + gridDim.x;
            if (tn < ntiles) {
                const int sn = tn << 6;
                int c = 0; while (c + 1 < CNUM && sn >= psL[c + 1]) ++c;
                stage_tile(data, idx, Xs[(ti + 1) & 1], sn, psL[c] + cntL[c] - 1, sw4, lane);
            }
            asm volatile("s_waitcnt vmcnt(0)" ::: "memory");
        } else {
            // ---- consume tile t from Xs[ti&1] ----
            const int slot0 = t << 6;
            int c = 0; while (c + 1 < CNUM && slot0 >= psL[c + 1]) ++c;
            const int relast = psL[c] + cntL[c] - 1;
            const int n16 = lane & 15, kg = lane >> 4;
            const int row = 16 * sw4 + n16;              // this lane's sample row
            const unsigned char* __restrict__ xrd = Xs[ti & 1] + (size_t)row * 1024;
            const int Sb = 16 * (n16 & 7);               // row&7 == n16&7
            const unsigned short* __restrict__ mb =
                mubf + ((size_t)c * KNUM + n16) * DDIM + 8 * kg;

            f32x4 acc[4] = {};
            float q = 0.f;
#pragma unroll
            for (int s = 0; s < 8; ++s) {
                const int off = 128 * s + 32 * kg;
                const float4 u0 = *(const float4*)(xrd + (off ^ Sb));
                const float4 u1 = *(const float4*)(xrd + ((off + 16) ^ Sb));
                const int d = 32 * s + 8 * kg;
                const float4 r0 = *(const float4*)(rstd + d);
                const float4 r1 = *(const float4*)(rstd + d + 4);
                const float4 m0 = *(const float4*)(mrs + d);
                const float4 m1 = *(const float4*)(mrs + d + 4);
                float a[8];
                a[0] = fmaf(u0.x, r0.x, -m0.x); a[1] = fmaf(u0.y, r0.y, -m0.y);
                a[2] = fmaf(u0.z, r0.z, -m0.z); a[3] = fmaf(u0.w, r0.w, -m0.w);
                a[4] = fmaf(u1.x, r1.x, -m1.x); a[5] = fmaf(u1.y, r1.y, -m1.y);
                a[6] = fmaf(u1.z, r1.z, -m1.z); a[7] = fmaf(u1.w, r1.w, -m1.w);
                union { short8 s8; __hip_bfloat162 b2[4]; } pk;
#pragma unroll
                for (int j = 0; j < 4; ++j) {
                    q = fmaf(a[2 * j], a[2 * j], q);
                    q = fmaf(a[2 * j + 1], a[2 * j + 1], q);
                    pk.b2[j] = __float22bfloat162_rn(float2{a[2 * j], a[2 * j + 1]});
                }
                short8 af0 = *(const short8*)(mb + 0 * 16 * DDIM + 32 * s);
                short8 af1 = *(const short8*)(mb + 1 * 16 * DDIM + 32 * s);
                short8 af2 = *(const short8*)(mb + 2 * 16 * DDIM + 32 * s);
                short8 af3 = *(const short8*)(mb + 3 * 16 * DDIM + 32 * s);
                acc[0] = __builtin_amdgcn_mfma_f32_16x16x32_bf16(af0, pk.s8, acc[0], 0, 0, 0);
                acc[1] = __builtin_amdgcn_mfma_f32_16x16x32_bf16(af1, pk.s8, acc[1], 0, 0, 0);
                acc[2] = __builtin_amdgcn_mfma_f32_16x16x32_bf16(af2, pk.s8, acc[2], 0, 0, 0);
                acc[3] = __builtin_amdgcn_mfma_f32_16x16x32_bf16(af3, pk.s8, acc[3], 0, 0, 0);
            }
            q += shfl_xor_f(q, 16);
            q += shfl_xor_f(q, 32);

            // epilogue: lane holds 16 k-values (k = 16f + 4kg + r) of its sample
            const int ckb = c * KNUM;
            float simv[16], lpv[16];
            float mxv = -3.4e38f;
#pragma unroll
            for (int f = 0; f < 4; ++f) {
                const int kb = ckb + 16 * f + 4 * kg;
                const float4 m2v = *(const float4*)(mu2 + kb);
                const float4 rtv = *(const float4*)(rtau + kb);
                const float4 ltv = *(const float4*)(ltau + kb);
                const float4 vlv = *(const float4*)(vldf + kb);
#pragma unroll
                for (int r = 0; r < 4; ++r) {
                    const float m2 = (&m2v.x)[r];
                    const float d2 = fmaxf(fmaf(-2.0f, acc[f][r], q + m2), 0.f);
                    const float dist = -6.25f * sqrtf(d2);   // 100/sqrt(256)
                    const float sim = ((&vlv.x)[r] > 0.5f) ? dist : -1.0e12f;
                    simv[4 * f + r] = sim;
                    lpv[4 * f + r] = fmaf(sim, (&rtv.x)[r], -(&ltv.x)[r]);
                    mxv = fmaxf(mxv, 0.5f * sim);
                }
            }
            mxv = fmaxf(mxv, shfl_xor_f(mxv, 16));
            mxv = fmaxf(mxv, shfl_xor_f(mxv, 32));
            float se = 0.f, sl = 0.f;
#pragma unroll
            for (int i = 0; i < 16; ++i) {
                const float e = __expf(fmaf(0.5f, simv[i], -mxv));
                se += e;
                sl = fmaf(e, lpv[i], sl);
            }
            se += shfl_xor_f(se, 16); se += shfl_xor_f(se, 32);
            sl += shfl_xor_f(sl, 16); sl += shfl_xor_f(sl, 32);
            const int slot = slot0 + row;
            float res = (kg == 0 && slot <= relast) ? (-sl / se) : 0.f;
            res += shfl_xor_f(res, 1);
            res += shfl_xor_f(res, 2);
            res += shfl_xor_f(res, 4);
            res += shfl_xor_f(res, 8);
            if (lane == 0) wpart[t * 4 + sw4] = res;
        }
        __syncthreads();                                  // swap buffers
    }
}

// ---- K_D: deterministic per-class reduce -> loss (recomputes scan from bc) ----
__global__ void k_final(const float* __restrict__ wpart, const int* __restrict__ bc,
                        float* __restrict__ out)
{
    __shared__ float seg[CNUM];
    __shared__ int clsc[CNUM];
    __shared__ int psl[CNUM + 1];
    const int t = threadIdx.x;
    if (t < CNUM) {
        int s = 0;
#pragma unroll 8
        for (int b = 0; b < NHB; ++b) s += bc[b * CNUM + t];
        clsc[t] = s;
    }
    __syncthreads();
    if (t == 0) {
        int run = 0;
        for (int c = 0; c < CNUM; ++c) { psl[c] = run; run += (clsc[c] + 63) & ~63; }
        psl[CNUM] = run;
    }
    __syncthreads();
    if (t < CNUM) {
        float s = 0.f;
        const int b0 = psl[t] >> 6, b1 = psl[t + 1] >> 6;
        for (int b = b0; b < b1; b++) {
            const float4 v = *(const float4*)(wpart + 4 * b);
            s += ((v.x + v.y) + (v.z + v.w));
        }
        seg[t] = s;
    }
    __syncthreads();
    if (t == 0) {
        float loss = 0.f;
        for (int c = 0; c < CNUM; c++) {
            const float cc = (float)clsc[c];
            if (cc > 0.f) loss += seg[c] / fmaxf(cc, 1.0f);
        }
        out[0] = loss;
    }
}

extern "C" void kernel_launch(void* const* d_in, const int* in_sizes, int n_in,
                              void* d_out, int out_size, void* d_ws, size_t ws_size,
                              hipStream_t stream)
{
    const float* data     = (const float*)d_in[0];
    const int*   labels   = (const int*)d_in[1];
    const float* mu       = (const float*)d_in[2];
    const float* exp_temp = (const float*)d_in[3];
    const float* med      = (const float*)d_in[4];
    const float* stdv     = (const float*)d_in[5];
    const float* runa     = (const float*)d_in[6];
    const float* runb     = (const float*)d_in[7];
    float* out = (float*)d_out;
    const int N = in_sizes[0] / DDIM;
    const int idx_slots = N + CNUM * 64;
    const int NB = (idx_slots + 63) / 64;                // tile upper bound

    char* w = (char*)d_ws;
    float* mu2  = (float*)w; w += (size_t)CNUM * KNUM * 4;
    float* rtau = (float*)w; w += (size_t)CNUM * KNUM * 4;
    float* ltau = (float*)w; w += (size_t)CNUM * KNUM * 4;
    float* vldf = (float*)w; w += (size_t)CNUM * KNUM * 4;
    float* rstd = (float*)w; w += (size_t)DDIM * 4;
    float* mrs  = (float*)w; w += (size_t)DDIM * 4;
    unsigned short* mubf = (unsigned short*)w; w += (size_t)CNUM * KNUM * DDIM * 2;
    int* bc  = (int*)w; w += (size_t)NHB * CNUM * 4;
    int* idx = (int*)w; w += (size_t)idx_slots * 4;
    float* wp = (float*)w; w += (size_t)NB * 4 * 4;

    k_setup<<<dim3(384), dim3(256), 0, stream>>>(
        mu, exp_temp, runa, runb, med, stdv, labels, N,
        mu2, rtau, ltau, vldf, rstd, mrs, mubf, bc);
    k_scatter<<<dim3(NHB), dim3(256), 0, stream>>>(labels, N, bc, idx);
    k_main<<<dim3(256), dim3(512), 0, stream>>>(
        data, mubf, mrs, rstd, mu2, rtau, ltau, vldf, idx, bc, wp);
    k_final<<<dim3(1), dim3(32), 0, stream>>>(wp, bc, out);
}